// Round 14
// baseline (228.764 us; speedup 1.0000x reference)
//
#include <hip/hip_runtime.h>

typedef short s16x8 __attribute__((ext_vector_type(8)));
typedef float f32x4 __attribute__((ext_vector_type(4)));
typedef float f32x16 __attribute__((ext_vector_type(16)));
typedef unsigned uint2v __attribute__((ext_vector_type(2)));
typedef unsigned short ushort_t;

#define CSC 0.18033688011112042f   // 0.125 * log2(e): softmax scale folded into exp2 domain
#define MFIX 16.0f                 // fixed softmax shift: exact (shift-invariant); overflow needs s>700

// fp32 -> bf16 round-to-nearest-even (finite inputs)
__device__ __forceinline__ ushort_t f2b(float f) {
    union { float f; unsigned int u; } c; c.f = f;
    unsigned int u = c.u;
    return (ushort_t)((u + 0x7fffu + ((u >> 16) & 1u)) >> 16);
}

__device__ __forceinline__ unsigned cvt_pk_bf16(float lo, float hi) {
    unsigned r;
    asm("v_cvt_pk_bf16_f32 %0, %1, %2" : "=v"(r) : "v"(lo), "v"(hi));
    return r;
}

__device__ __forceinline__ float asf(unsigned u) { union { unsigned u; float f; } c; c.u = u; return c.f; }
__device__ __forceinline__ unsigned asu(float f) { union { float f; unsigned u; } c; c.f = f; return c.u; }

// swaps a.hi-lanes with b.lo-lanes; for v=v: {x,y} = {own,partner(lane^32)} on every lane
__device__ __forceinline__ uint2v pl32swap(unsigned a, unsigned b) {
#if __has_builtin(__builtin_amdgcn_permlane32_swap)
    return __builtin_amdgcn_permlane32_swap(a, b, false, false);
#else
    asm volatile("v_permlane32_swap_b32 %0, %1" : "+v"(a), "+v"(b));
    uint2v r; r.x = a; r.y = b; return r;
#endif
}

__device__ __forceinline__ void gload_lds16(const void* g, void* lds) {
    __builtin_amdgcn_global_load_lds(
        (const __attribute__((address_space(1))) unsigned int*)g,
        (__attribute__((address_space(3))) unsigned int*)lds, 16, 0, 0);
}

// ---------------- fp32 -> bf16 conversion ----------------
__global__ __launch_bounds__(256) void cvt_kernel(const float* __restrict__ src,
                                                  ushort_t* __restrict__ dst, int n) {
    int i = (blockIdx.x * 256 + threadIdx.x) * 4;
    if (i >= n) return;
    float4 v = *(const float4*)&src[i];
    ushort4 o = make_ushort4(f2b(v.x), f2b(v.y), f2b(v.z), f2b(v.w));
    *(ushort4*)&dst[i] = o;
}

// all four weight matrices in one launch (grid.y selects)
__global__ __launch_bounds__(256) void cvt4_kernel(const float* __restrict__ W0,
                                                   const float* __restrict__ W1,
                                                   const float* __restrict__ W2,
                                                   const float* __restrict__ W3,
                                                   ushort_t* __restrict__ D0,
                                                   ushort_t* __restrict__ D1,
                                                   ushort_t* __restrict__ D2,
                                                   ushort_t* __restrict__ D3) {
    const int w = blockIdx.y;
    const float* src = (w == 0) ? W0 : (w == 1) ? W1 : (w == 2) ? W2 : W3;
    ushort_t* dst = (w == 0) ? D0 : (w == 1) ? D1 : (w == 2) ? D2 : D3;
    int i = (blockIdx.x * 256 + threadIdx.x) * 4;
    float4 v = *(const float4*)&src[i];
    ushort4 o = make_ushort4(f2b(v.x), f2b(v.y), f2b(v.z), f2b(v.w));
    *(ushort4*)&dst[i] = o;
}

// ---------------- GEMM staging: one 128x32 A-tile chunk + B-tile chunk per thread x2 ----------
// Issues 4 global_load_lds per wave per call.
__device__ __forceinline__ void stage_gemm(const ushort_t* __restrict__ A,
                                           const ushort_t* __restrict__ B,
                                           int row0, int tileN, int K, int kt,
                                           ushort_t* As, ushort_t* Bs, int tid) {
#pragma unroll
    for (int i = 0; i < 2; ++i) {
        int c = i * 256 + tid;             // 512 chunks of 16B per 8KB tile
        int r = c >> 2;                    // row 0..127
        int scc = (c & 3) ^ ((r >> 1) & 3);
        gload_lds16(A + (size_t)(row0 + r) * K + kt + scc * 8, As + c * 8);
        gload_lds16(B + (size_t)(tileN + r) * K + kt + scc * 8, Bs + c * 8);
    }
}

// ---------------- shared GEMM main loop: C[128,128] = A[M,K] * B[N,K]^T ----------------
__device__ __forceinline__ void gemm_mainloop(const ushort_t* __restrict__ A,
                                              const ushort_t* __restrict__ B,
                                              int row0, int tileN, int K,
                                              ushort_t* As, ushort_t* Bs,   // 3 buffers, stride 4096 elems
                                              f32x4 acc[4][4]) {
    const int tid = threadIdx.x;
    const int lane = tid & 63;
    const int wid = tid >> 6;
    const int wrow = wid >> 1, wcol = wid & 1;
    const int nT = K >> 5;

    stage_gemm(A, B, row0, tileN, K, 0, As, Bs, tid);
    stage_gemm(A, B, row0, tileN, K, 32, As + 4096, Bs + 4096, tid);

    int cur = 0, nx2 = 2;
    for (int t = 0; t < nT; ++t) {
        // tile t's 4 loads done; tile t+1's 4 stay in flight across the barrier
        asm volatile("s_waitcnt vmcnt(4)" ::: "memory");
        __builtin_amdgcn_sched_barrier(0);
        __builtin_amdgcn_s_barrier();
        __builtin_amdgcn_sched_barrier(0);

        int tn = (t + 2 < nT) ? t + 2 : nT - 1;
        stage_gemm(A, B, row0, tileN, K, tn * 32, As + nx2 * 4096, Bs + nx2 * 4096, tid);

        const ushort_t* Ab = As + cur * 4096;
        const ushort_t* Bb = Bs + cur * 4096;

        s16x8 af[4], bfr[4];
#pragma unroll
        for (int m = 0; m < 4; ++m) {
            int row = wrow * 64 + m * 16 + (lane & 15);
            af[m] = *(const s16x8*)&Ab[row * 32 + (((lane >> 4) ^ ((row >> 1) & 3)) * 8)];
        }
#pragma unroll
        for (int n = 0; n < 4; ++n) {
            int row = wcol * 64 + n * 16 + (lane & 15);
            bfr[n] = *(const s16x8*)&Bb[row * 32 + (((lane >> 4) ^ ((row >> 1) & 3)) * 8)];
        }
#pragma unroll
        for (int m = 0; m < 4; ++m)
#pragma unroll
            for (int n = 0; n < 4; ++n)
                acc[m][n] = __builtin_amdgcn_mfma_f32_16x16x32_bf16(af[m], bfr[n], acc[m][n], 0, 0, 0);

        cur = (cur == 2) ? 0 : cur + 1;
        nx2 = (nx2 == 2) ? 0 : nx2 + 1;
    }
}

// ---------------- QKV projection ----------------
// Q,K scatter to [B,H,N,64] bf16; V written TRANSPOSED to [B,H,64,N] bf16.
// Epilogue bounces the C-tile through the (idle) staging LDS so ALL global stores are
// coalesced 16B chunks (256B per 16-lane group) instead of scattered 2B/8B writes.
__global__ __launch_bounds__(256) void gemm_qkv(const ushort_t* __restrict__ X,
                                                const ushort_t* __restrict__ Wq,
                                                const ushort_t* __restrict__ Wk,
                                                const ushort_t* __restrict__ Wv,
                                                const float* __restrict__ bq,
                                                const float* __restrict__ bk,
                                                const float* __restrict__ bv,
                                                ushort_t* __restrict__ Qb,
                                                ushort_t* __restrict__ Kb,
                                                ushort_t* __restrict__ VTb) {
    __shared__ ushort_t Smem[2 * 3 * 128 * 32];   // staging pool (49152 B); reused as C-tile
    ushort_t* As = Smem;
    ushort_t* Bs = Smem + 3 * 4096;
    const int K = 1024;
    const int tid = threadIdx.x;
    const int lane = tid & 63;
    const int wid = tid >> 6;
    const int wrow = wid >> 1, wcol = wid & 1;
    const int row0 = blockIdx.x * 128;
    const int wsel = blockIdx.y >> 3;
    const int tileN = (blockIdx.y & 7) * 128;
    const ushort_t* B = (wsel == 0) ? Wq : (wsel == 1 ? Wk : Wv);
    const float* bias = (wsel == 0) ? bq : (wsel == 1 ? bk : bv);

    f32x4 acc[4][4] = {};
    gemm_mainloop(X, B, row0, tileN, K, As, Bs, acc);

    // drain in-flight dup-stage DMA, then all waves done with fragment reads -> LDS reusable
    asm volatile("s_waitcnt vmcnt(0)" ::: "memory");
    __syncthreads();

    ushort_t* Ct = Smem;                   // 128 x (128+8) bf16 tile, padded stride 136

    if (wsel == 2) {
        // transpose into LDS: Ct[col][row]; per-lane 4 r-values are row-contiguous -> b64 writes
#pragma unroll
        for (int m = 0; m < 4; ++m)
#pragma unroll
            for (int n = 0; n < 4; ++n) {
                int lrow = wrow * 64 + m * 16 + (lane >> 4) * 4;
                int lcol = wcol * 64 + n * 16 + (lane & 15);
                float bi = bias[tileN + lcol];
                ushort4 w;
                w.x = f2b(acc[m][n][0] + bi);
                w.y = f2b(acc[m][n][1] + bi);
                w.z = f2b(acc[m][n][2] + bi);
                w.w = f2b(acc[m][n][3] + bi);
                *(ushort4*)&Ct[lcol * 136 + lrow] = w;
            }
        __syncthreads();
        // coalesced store: rows of V^T are contiguous along nn
#pragma unroll
        for (int it = 0; it < 8; ++it) {
            int cid = it * 256 + tid;
            int lcol = cid >> 4;           // gcol_local 0..127
            int ch = cid & 15;             // 16B chunk along nn
            int gcol = tileN + lcol;
            int hh = gcol >> 6, hd = gcol & 63;
            int grow = row0 + ch * 8;
            int bb = grow >> 11, nn = grow & 2047;
            uint4 v = *(const uint4*)&Ct[lcol * 136 + ch * 8];
            *(uint4*)&VTb[((size_t)((bb * 16 + hh) * 64 + hd)) * 2048 + nn] = v;
        }
    } else {
        ushort_t* dst = (wsel == 0) ? Qb : Kb;
#pragma unroll
        for (int m = 0; m < 4; ++m)
#pragma unroll
            for (int n = 0; n < 4; ++n) {
                int lrow = wrow * 64 + m * 16 + (lane >> 4) * 4;
                int lcol = wcol * 64 + n * 16 + (lane & 15);
                float bi = bias[tileN + lcol];
#pragma unroll
                for (int r = 0; r < 4; ++r)
                    Ct[(lrow + r) * 136 + lcol] = f2b(acc[m][n][r] + bi);
            }
        __syncthreads();
        // coalesced store: rows of Q/K are contiguous along hd (two 128B head-segments per row)
#pragma unroll
        for (int it = 0; it < 8; ++it) {
            int cid = it * 256 + tid;
            int lrow = cid >> 4;           // 0..127
            int ch = cid & 15;             // 16B chunk along the 128 cols
            int grow = row0 + lrow;
            int gcol = tileN + ch * 8;
            int bb = grow >> 11, nn = grow & 2047;
            int hh = gcol >> 6, hd = gcol & 63;
            uint4 v = *(const uint4*)&Ct[lrow * 136 + ch * 8];
            *(uint4*)&dst[((size_t)((bb * 16 + hh) * 2048 + nn)) * 64 + hd] = v;
        }
    }
}

// ---------------- output projection: fp32 out + bias ----------------
__global__ __launch_bounds__(256) void gemm_out(const ushort_t* __restrict__ A,
                                                const ushort_t* __restrict__ B,
                                                const float* __restrict__ bias,
                                                float* __restrict__ out) {
    __shared__ ushort_t As[3 * 128 * 32];
    __shared__ ushort_t Bs[3 * 128 * 32];
    const int K = 1024;
    const int lane = threadIdx.x & 63;
    const int wid = threadIdx.x >> 6;
    const int wrow = wid >> 1, wcol = wid & 1;
    const int row0 = blockIdx.x * 128;
    const int tileN = blockIdx.y * 128;

    f32x4 acc[4][4] = {};
    gemm_mainloop(A, B, row0, tileN, K, As, Bs, acc);

#pragma unroll
    for (int m = 0; m < 4; ++m)
#pragma unroll
        for (int n = 0; n < 4; ++n)
#pragma unroll
            for (int r = 0; r < 4; ++r) {
                int grow = row0 + wrow * 64 + m * 16 + (lane >> 4) * 4 + r;
                int gcol = tileN + wcol * 64 + n * 16 + (lane & 15);
                out[(size_t)grow * 1024 + gcol] = acc[m][n][r] + bias[gcol];
            }
}

// ---------------- attention staging: K tile + V^T tile, source-side XOR swizzle ----------------
// 512 threads: each thread stages exactly one 16B chunk of K and one of V^T per tile.
__device__ __forceinline__ void stage_tile(const ushort_t* __restrict__ Kg,
                                           const ushort_t* __restrict__ VTg,
                                           ushort_t* KsB, ushort_t* VsB,
                                           int k0, int tid) {
    int r = tid >> 3;                  // row 0..63
    int scc = (tid & 7) ^ (r & 7);     // swizzled 16B-chunk within the row
    gload_lds16(Kg + (size_t)(k0 + r) * 64 + scc * 8, KsB + tid * 8);
    gload_lds16(VTg + (size_t)r * 2048 + k0 + scc * 8, VsB + tid * 8);
}

// ---------------- flash attention fwd (swapped-QK^T 32x32, fixed-shift in-register softmax) ----
// ROUND-13 BODY + HALVED SYNC FREQUENCY: 4 LDS buffers (tile t <-> buf t&3); ONE
// vmcnt(0)+barrier per TWO tiles; the two bodies run strictly sequentially (sched_barrier(0)
// between them pins separation so both tiles' score registers are never co-live -> no spill).
__global__ __launch_bounds__(512, 4) void attn_kernel(const ushort_t* __restrict__ Qb,
                                                      const ushort_t* __restrict__ Kb,
                                                      const ushort_t* __restrict__ VTb,
                                                      ushort_t* __restrict__ Ob) {
    const int fid = blockIdx.x;
    const int xcd = fid & 7;
    const int slot = fid >> 3;                 // 0..63
    const int qtile = slot & 7;                // 8 q-tiles of 256 rows
    const int bh = (xcd << 3) + (slot >> 3);   // per-XCD K/V working set ~4MB (L2-fit)
    const int q0 = qtile * 256;
    const int tid = threadIdx.x;
    const int lane = tid & 63;
    const int wid = tid >> 6;                  // 0..7
    const int q31 = lane & 31;
    const int hi = lane >> 5;
    const int rsw = q31 & 7;
    const int b = bh >> 4, h = bh & 15;

    const ushort_t* Q = Qb + (size_t)bh * 2048 * 64;
    const ushort_t* K = Kb + (size_t)bh * 2048 * 64;
    const ushort_t* VT = VTb + (size_t)bh * 64 * 2048;

    __shared__ ushort_t Ksh[4][64 * 64];   // K tile [k][d], chunk-swizzled content; buf = t&3
    __shared__ ushort_t Vsh[4][64 * 64];   // V^T tile [d][k], chunk-swizzled content

    const int qw = q0 + wid * 32;

    // Q B-fragments (col=q=lane&31, k-rows d = ds*16 + hi*8 + j) — resident all loop
    s16x8 qf[4];
#pragma unroll
    for (int ds = 0; ds < 4; ++ds)
        qf[ds] = *(const s16x8*)&Q[(size_t)(qw + q31) * 64 + ds * 16 + hi * 8];

    // ones B-fragment (bf16 1.0 = 0x3F80) for the P*1 row-sum MFMA
    s16x8 ones;
#pragma unroll
    for (int j = 0; j < 8; ++j) ones[j] = (short)0x3F80;

    f32x16 o[2] = {};          // O[q-rows][d = db*32 + q31]
    f32x16 la = {};            // row-sum accumulator; same C-layout as o (all cols identical)

    stage_tile(K, VT, Ksh[0], Vsh[0], 0, tid);
    stage_tile(K, VT, Ksh[1], Vsh[1], 64, tid);

    const float negmc = -MFIX * CSC;   // fixed softmax shift (exp2 domain)

    for (int i = 0; i < 16; ++i) {
        // drain the 4 loads for tiles 2i,2i+1 (issued one full interval ago)
        asm volatile("s_waitcnt vmcnt(0)" ::: "memory");
        __builtin_amdgcn_sched_barrier(0);
        __builtin_amdgcn_s_barrier();      // all waves done with interval i-1 => its 2 bufs free
        __builtin_amdgcn_sched_barrier(0);

        // stage tiles 2i+2, 2i+3 into the buffers consumed in interval i-1 (tail: clamped dups)
        {
            int sa0 = (2 * i + 2 <= 31) ? 2 * i + 2 : 31;
            int sa1 = (2 * i + 3 <= 31) ? 2 * i + 3 : 31;
            stage_tile(K, VT, Ksh[(2 * i + 2) & 3], Vsh[(2 * i + 2) & 3], sa0 * 64, tid);
            stage_tile(K, VT, Ksh[(2 * i + 3) & 3], Vsh[(2 * i + 3) & 3], sa1 * 64, tid);
        }

#pragma unroll
        for (int half = 0; half < 2; ++half) {
            const int t = 2 * i + half;
            const ushort_t* KB = Ksh[t & 3];
            const ushort_t* VB = Vsh[t & 3];

            // ---- QK^T: S[k][q], A = K-frag (row k = kb*32 + lane&31), B = Q-frag ----
            f32x16 sa[2];
            sa[0] = (f32x16)0.f; sa[1] = (f32x16)0.f;
            __builtin_amdgcn_s_setprio(1);
#pragma unroll
            for (int kb = 0; kb < 2; ++kb)
#pragma unroll
                for (int ds = 0; ds < 4; ++ds) {
                    s16x8 kfr = *(const s16x8*)&KB[(kb * 32 + q31) * 64 + (((2 * ds + hi) ^ rsw) * 8)];
                    sa[kb] = __builtin_amdgcn_mfma_f32_32x32x16_bf16(kfr, qf[ds], sa[kb], 0, 0, 0);
                }
            __builtin_amdgcn_s_setprio(0);

            // ---- exp (fixed shift) + pack to PV A-fragments (T12); sum via ones-MFMA ----
            s16x8 pa[4];
#pragma unroll
            for (int kb = 0; kb < 2; ++kb) {
                float p[16];
#pragma unroll
                for (int r = 0; r < 16; ++r)
                    p[r] = exp2f(fmaf(sa[kb][r], CSC, negmc));
#pragma unroll
                for (int s = 0; s < 2; ++s) {
                    unsigned a0 = cvt_pk_bf16(p[8 * s + 0], p[8 * s + 1]);
                    unsigned b0 = cvt_pk_bf16(p[8 * s + 4], p[8 * s + 5]);
                    unsigned a1 = cvt_pk_bf16(p[8 * s + 2], p[8 * s + 3]);
                    unsigned b1 = cvt_pk_bf16(p[8 * s + 6], p[8 * s + 7]);
                    uint2v w02 = pl32swap(a0, b0);   // -> word0, word2
                    uint2v w13 = pl32swap(a1, b1);   // -> word1, word3
                    union { unsigned u[4]; s16x8 v; } fr;
                    fr.u[0] = w02.x; fr.u[1] = w13.x; fr.u[2] = w02.y; fr.u[3] = w13.y;
                    pa[kb * 2 + s] = fr.v;
                }
            }

            // ---- PV: O[q][d] += P * V; la += P * 1 (row-sum on the matrix pipe) ----
            __builtin_amdgcn_s_setprio(1);
#pragma unroll
            for (int s = 0; s < 4; ++s) {
#pragma unroll
                for (int db = 0; db < 2; ++db) {
                    s16x8 vfr = *(const s16x8*)&VB[(db * 32 + q31) * 64 + (((2 * s + hi) ^ rsw) * 8)];
                    o[db] = __builtin_amdgcn_mfma_f32_32x32x16_bf16(pa[s], vfr, o[db], 0, 0, 0);
                }
                la = __builtin_amdgcn_mfma_f32_32x32x16_bf16(pa[s], ones, la, 0, 0, 0);
            }
            __builtin_amdgcn_s_setprio(0);

            // pin separation between the two bodies: keeps only ONE tile's scores live
            __builtin_amdgcn_sched_barrier(0);
        }
    }

    // drain outstanding tail DMA before kernel end
    asm volatile("s_waitcnt vmcnt(0)" ::: "memory");

    // ---- epilogue: la[r] is l for the same C-layout row as o[*][r] -> direct normalize ----
#pragma unroll
    for (int g = 0; g < 4; ++g) {
#pragma unroll
        for (int j = 0; j < 4; ++j) {
            int r = g * 4 + j;
            float inv = 1.0f / la[r];
            int qrow = qw + hi * 4 + g * 8 + j;
            size_t base = ((size_t)(b * 2048 + qrow)) * 1024 + h * 64 + q31;
            Ob[base] = f2b(o[0][r] * inv);
            Ob[base + 32] = f2b(o[1][r] * inv);
        }
    }
}

// ---------------- launcher ----------------
extern "C" void kernel_launch(void* const* d_in, const int* in_sizes, int n_in,
                              void* d_out, int out_size, void* d_ws, size_t ws_size,
                              hipStream_t stream) {
    const float* x  = (const float*)d_in[0];
    const float* Wq = (const float*)d_in[1];
    const float* bq = (const float*)d_in[2];
    const float* Wk = (const float*)d_in[3];
    const float* bk = (const float*)d_in[4];
    const float* Wv = (const float*)d_in[5];
    const float* bv = (const float*)d_in[6];
    const float* Wo = (const float*)d_in[7];
    const float* bo = (const float*)d_in[8];
    float* out = (float*)d_out;

    const size_t XN = (size_t)8192 * 1024;
    const size_t WN = (size_t)1024 * 1024;

    ushort_t* Xb  = (ushort_t*)d_ws;
    ushort_t* Wqb = Xb + XN;
    ushort_t* Wkb = Wqb + WN;
    ushort_t* Wvb = Wkb + WN;
    ushort_t* Wob = Wvb + WN;
    ushort_t* Qb  = Wob + WN;
    ushort_t* Kb  = Qb + XN;
    ushort_t* VTb = Kb + XN;   // V transposed: [B,H,64,2048]
    ushort_t* Ob  = VTb + XN;

    cvt_kernel<<<(int)(XN / 4 / 256), 256, 0, stream>>>(x, Xb, (int)XN);
    dim3 gc((int)(WN / 4 / 256), 4);
    cvt4_kernel<<<gc, 256, 0, stream>>>(Wq, Wk, Wv, Wo, Wqb, Wkb, Wvb, Wob);

    dim3 g1(64, 24);
    gemm_qkv<<<g1, 256, 0, stream>>>(Xb, Wqb, Wkb, Wvb, bq, bk, bv, Qb, Kb, VTb);

    attn_kernel<<<512, 512, 0, stream>>>(Qb, Kb, VTb, Ob);

    dim3 g3(64, 8);
    gemm_out<<<g3, 256, 0, stream>>>(Ob, Wob, bo, out);
}

// Round 15
// 223.418 us; speedup vs baseline: 1.0239x; 1.0239x over previous
//
#include <hip/hip_runtime.h>

typedef short s16x8 __attribute__((ext_vector_type(8)));
typedef float f32x4 __attribute__((ext_vector_type(4)));
typedef float f32x16 __attribute__((ext_vector_type(16)));
typedef unsigned uint2v __attribute__((ext_vector_type(2)));
typedef unsigned short ushort_t;

#define CSC 0.18033688011112042f   // 0.125 * log2(e): softmax scale folded into exp2 domain
#define MFIX 16.0f                 // fixed softmax shift: exact (shift-invariant); overflow needs s>700

// fp32 -> bf16 round-to-nearest-even (finite inputs)
__device__ __forceinline__ ushort_t f2b(float f) {
    union { float f; unsigned int u; } c; c.f = f;
    unsigned int u = c.u;
    return (ushort_t)((u + 0x7fffu + ((u >> 16) & 1u)) >> 16);
}

__device__ __forceinline__ unsigned cvt_pk_bf16(float lo, float hi) {
    unsigned r;
    asm("v_cvt_pk_bf16_f32 %0, %1, %2" : "=v"(r) : "v"(lo), "v"(hi));
    return r;
}

__device__ __forceinline__ float asf(unsigned u) { union { unsigned u; float f; } c; c.u = u; return c.f; }
__device__ __forceinline__ unsigned asu(float f) { union { float f; unsigned u; } c; c.f = f; return c.u; }

// swaps a.hi-lanes with b.lo-lanes; for v=v: {x,y} = {own,partner(lane^32)} on every lane
__device__ __forceinline__ uint2v pl32swap(unsigned a, unsigned b) {
#if __has_builtin(__builtin_amdgcn_permlane32_swap)
    return __builtin_amdgcn_permlane32_swap(a, b, false, false);
#else
    asm volatile("v_permlane32_swap_b32 %0, %1" : "+v"(a), "+v"(b));
    uint2v r; r.x = a; r.y = b; return r;
#endif
}

__device__ __forceinline__ void gload_lds16(const void* g, void* lds) {
    __builtin_amdgcn_global_load_lds(
        (const __attribute__((address_space(1))) unsigned int*)g,
        (__attribute__((address_space(3))) unsigned int*)lds, 16, 0, 0);
}

// ---------------- fp32 -> bf16 conversion ----------------
__global__ __launch_bounds__(256) void cvt_kernel(const float* __restrict__ src,
                                                  ushort_t* __restrict__ dst, int n) {
    int i = (blockIdx.x * 256 + threadIdx.x) * 4;
    if (i >= n) return;
    float4 v = *(const float4*)&src[i];
    ushort4 o = make_ushort4(f2b(v.x), f2b(v.y), f2b(v.z), f2b(v.w));
    *(ushort4*)&dst[i] = o;
}

// all four weight matrices in one launch (grid.y selects)
__global__ __launch_bounds__(256) void cvt4_kernel(const float* __restrict__ W0,
                                                   const float* __restrict__ W1,
                                                   const float* __restrict__ W2,
                                                   const float* __restrict__ W3,
                                                   ushort_t* __restrict__ D0,
                                                   ushort_t* __restrict__ D1,
                                                   ushort_t* __restrict__ D2,
                                                   ushort_t* __restrict__ D3) {
    const int w = blockIdx.y;
    const float* src = (w == 0) ? W0 : (w == 1) ? W1 : (w == 2) ? W2 : W3;
    ushort_t* dst = (w == 0) ? D0 : (w == 1) ? D1 : (w == 2) ? D2 : D3;
    int i = (blockIdx.x * 256 + threadIdx.x) * 4;
    float4 v = *(const float4*)&src[i];
    ushort4 o = make_ushort4(f2b(v.x), f2b(v.y), f2b(v.z), f2b(v.w));
    *(ushort4*)&dst[i] = o;
}

// ---------------- GEMM staging: one 128x32 A-tile chunk + B-tile chunk per thread x2 ----------
// Issues 4 global_load_lds per wave per call.
__device__ __forceinline__ void stage_gemm(const ushort_t* __restrict__ A,
                                           const ushort_t* __restrict__ B,
                                           int row0, int tileN, int K, int kt,
                                           ushort_t* As, ushort_t* Bs, int tid) {
#pragma unroll
    for (int i = 0; i < 2; ++i) {
        int c = i * 256 + tid;             // 512 chunks of 16B per 8KB tile
        int r = c >> 2;                    // row 0..127
        int scc = (c & 3) ^ ((r >> 1) & 3);
        gload_lds16(A + (size_t)(row0 + r) * K + kt + scc * 8, As + c * 8);
        gload_lds16(B + (size_t)(tileN + r) * K + kt + scc * 8, Bs + c * 8);
    }
}

// ---------------- shared GEMM main loop: C[128,128] = A[M,K] * B[N,K]^T ----------------
__device__ __forceinline__ void gemm_mainloop(const ushort_t* __restrict__ A,
                                              const ushort_t* __restrict__ B,
                                              int row0, int tileN, int K,
                                              ushort_t* As, ushort_t* Bs,   // 3 buffers, stride 4096 elems
                                              f32x4 acc[4][4]) {
    const int tid = threadIdx.x;
    const int lane = tid & 63;
    const int wid = tid >> 6;
    const int wrow = wid >> 1, wcol = wid & 1;
    const int nT = K >> 5;

    stage_gemm(A, B, row0, tileN, K, 0, As, Bs, tid);
    stage_gemm(A, B, row0, tileN, K, 32, As + 4096, Bs + 4096, tid);

    int cur = 0, nx2 = 2;
    for (int t = 0; t < nT; ++t) {
        // tile t's 4 loads done; tile t+1's 4 stay in flight across the barrier
        asm volatile("s_waitcnt vmcnt(4)" ::: "memory");
        __builtin_amdgcn_sched_barrier(0);
        __builtin_amdgcn_s_barrier();
        __builtin_amdgcn_sched_barrier(0);

        int tn = (t + 2 < nT) ? t + 2 : nT - 1;
        stage_gemm(A, B, row0, tileN, K, tn * 32, As + nx2 * 4096, Bs + nx2 * 4096, tid);

        const ushort_t* Ab = As + cur * 4096;
        const ushort_t* Bb = Bs + cur * 4096;

        s16x8 af[4], bfr[4];
#pragma unroll
        for (int m = 0; m < 4; ++m) {
            int row = wrow * 64 + m * 16 + (lane & 15);
            af[m] = *(const s16x8*)&Ab[row * 32 + (((lane >> 4) ^ ((row >> 1) & 3)) * 8)];
        }
#pragma unroll
        for (int n = 0; n < 4; ++n) {
            int row = wcol * 64 + n * 16 + (lane & 15);
            bfr[n] = *(const s16x8*)&Bb[row * 32 + (((lane >> 4) ^ ((row >> 1) & 3)) * 8)];
        }
#pragma unroll
        for (int m = 0; m < 4; ++m)
#pragma unroll
            for (int n = 0; n < 4; ++n)
                acc[m][n] = __builtin_amdgcn_mfma_f32_16x16x32_bf16(af[m], bfr[n], acc[m][n], 0, 0, 0);

        cur = (cur == 2) ? 0 : cur + 1;
        nx2 = (nx2 == 2) ? 0 : nx2 + 1;
    }
}

// ---------------- QKV projection ----------------
// Q,K scatter to [B,H,N,64] bf16; V written TRANSPOSED to [B,H,64,N] bf16.
// Epilogue bounces the C-tile through the (idle) staging LDS so ALL global stores are
// coalesced 16B chunks (256B per 16-lane group) instead of scattered 2B/8B writes.
__global__ __launch_bounds__(256) void gemm_qkv(const ushort_t* __restrict__ X,
                                                const ushort_t* __restrict__ Wq,
                                                const ushort_t* __restrict__ Wk,
                                                const ushort_t* __restrict__ Wv,
                                                const float* __restrict__ bq,
                                                const float* __restrict__ bk,
                                                const float* __restrict__ bv,
                                                ushort_t* __restrict__ Qb,
                                                ushort_t* __restrict__ Kb,
                                                ushort_t* __restrict__ VTb) {
    __shared__ ushort_t Smem[2 * 3 * 128 * 32];   // staging pool (49152 B); reused as C-tile
    ushort_t* As = Smem;
    ushort_t* Bs = Smem + 3 * 4096;
    const int K = 1024;
    const int tid = threadIdx.x;
    const int lane = tid & 63;
    const int wid = tid >> 6;
    const int wrow = wid >> 1, wcol = wid & 1;
    const int row0 = blockIdx.x * 128;
    const int wsel = blockIdx.y >> 3;
    const int tileN = (blockIdx.y & 7) * 128;
    const ushort_t* B = (wsel == 0) ? Wq : (wsel == 1 ? Wk : Wv);
    const float* bias = (wsel == 0) ? bq : (wsel == 1 ? bk : bv);

    f32x4 acc[4][4] = {};
    gemm_mainloop(X, B, row0, tileN, K, As, Bs, acc);

    // drain in-flight dup-stage DMA, then all waves done with fragment reads -> LDS reusable
    asm volatile("s_waitcnt vmcnt(0)" ::: "memory");
    __syncthreads();

    ushort_t* Ct = Smem;                   // 128 x (128+8) bf16 tile, padded stride 136

    if (wsel == 2) {
        // transpose into LDS: Ct[col][row]; per-lane 4 r-values are row-contiguous -> b64 writes
#pragma unroll
        for (int m = 0; m < 4; ++m)
#pragma unroll
            for (int n = 0; n < 4; ++n) {
                int lrow = wrow * 64 + m * 16 + (lane >> 4) * 4;
                int lcol = wcol * 64 + n * 16 + (lane & 15);
                float bi = bias[tileN + lcol];
                ushort4 w;
                w.x = f2b(acc[m][n][0] + bi);
                w.y = f2b(acc[m][n][1] + bi);
                w.z = f2b(acc[m][n][2] + bi);
                w.w = f2b(acc[m][n][3] + bi);
                *(ushort4*)&Ct[lcol * 136 + lrow] = w;
            }
        __syncthreads();
        // coalesced store: rows of V^T are contiguous along nn
#pragma unroll
        for (int it = 0; it < 8; ++it) {
            int cid = it * 256 + tid;
            int lcol = cid >> 4;           // gcol_local 0..127
            int ch = cid & 15;             // 16B chunk along nn
            int gcol = tileN + lcol;
            int hh = gcol >> 6, hd = gcol & 63;
            int grow = row0 + ch * 8;
            int bb = grow >> 11, nn = grow & 2047;
            uint4 v = *(const uint4*)&Ct[lcol * 136 + ch * 8];
            *(uint4*)&VTb[((size_t)((bb * 16 + hh) * 64 + hd)) * 2048 + nn] = v;
        }
    } else {
        ushort_t* dst = (wsel == 0) ? Qb : Kb;
#pragma unroll
        for (int m = 0; m < 4; ++m)
#pragma unroll
            for (int n = 0; n < 4; ++n) {
                int lrow = wrow * 64 + m * 16 + (lane >> 4) * 4;
                int lcol = wcol * 64 + n * 16 + (lane & 15);
                float bi = bias[tileN + lcol];
#pragma unroll
                for (int r = 0; r < 4; ++r)
                    Ct[(lrow + r) * 136 + lcol] = f2b(acc[m][n][r] + bi);
            }
        __syncthreads();
        // coalesced store: rows of Q/K are contiguous along hd (two 128B head-segments per row)
#pragma unroll
        for (int it = 0; it < 8; ++it) {
            int cid = it * 256 + tid;
            int lrow = cid >> 4;           // 0..127
            int ch = cid & 15;             // 16B chunk along the 128 cols
            int grow = row0 + lrow;
            int gcol = tileN + ch * 8;
            int bb = grow >> 11, nn = grow & 2047;
            int hh = gcol >> 6, hd = gcol & 63;
            uint4 v = *(const uint4*)&Ct[lrow * 136 + ch * 8];
            *(uint4*)&dst[((size_t)((bb * 16 + hh) * 2048 + nn)) * 64 + hd] = v;
        }
    }
}

// ---------------- output projection: fp32 out + bias ----------------
__global__ __launch_bounds__(256) void gemm_out(const ushort_t* __restrict__ A,
                                                const ushort_t* __restrict__ B,
                                                const float* __restrict__ bias,
                                                float* __restrict__ out) {
    __shared__ ushort_t As[3 * 128 * 32];
    __shared__ ushort_t Bs[3 * 128 * 32];
    const int K = 1024;
    const int lane = threadIdx.x & 63;
    const int wid = threadIdx.x >> 6;
    const int wrow = wid >> 1, wcol = wid & 1;
    const int row0 = blockIdx.x * 128;
    const int tileN = blockIdx.y * 128;

    f32x4 acc[4][4] = {};
    gemm_mainloop(A, B, row0, tileN, K, As, Bs, acc);

#pragma unroll
    for (int m = 0; m < 4; ++m)
#pragma unroll
        for (int n = 0; n < 4; ++n)
#pragma unroll
            for (int r = 0; r < 4; ++r) {
                int grow = row0 + wrow * 64 + m * 16 + (lane >> 4) * 4 + r;
                int gcol = tileN + wcol * 64 + n * 16 + (lane & 15);
                out[(size_t)grow * 1024 + gcol] = acc[m][n][r] + bias[gcol];
            }
}

// ---------------- attention staging: K tile + V^T tile, source-side XOR swizzle ----------------
// 512 threads: each thread stages exactly one 16B chunk of K and one of V^T per tile.
__device__ __forceinline__ void stage_tile(const ushort_t* __restrict__ Kg,
                                           const ushort_t* __restrict__ VTg,
                                           ushort_t* KsB, ushort_t* VsB,
                                           int k0, int tid) {
    int r = tid >> 3;                  // row 0..63
    int scc = (tid & 7) ^ (r & 7);     // swizzled 16B-chunk within the row
    gload_lds16(Kg + (size_t)(k0 + r) * 64 + scc * 8, KsB + tid * 8);
    gload_lds16(VTg + (size_t)r * 2048 + k0 + scc * 8, VsB + tid * 8);
}

// ---------------- flash attention fwd (swapped-QK^T 32x32, fixed-shift in-register softmax) ----
// ROUND-14 STRUCTURE + kb-SPLIT QK^T: per tile, QK(kb)->exp/pack(kb) sequentially so only ONE
// f32x16 score block is live -> peak regs ~128/wave -> 2 blocks/CU resident (4 waves/SIMD TLP).
// Bonus: exp/pack(kb0) VALU overlaps QK(kb1) MFMA (independent, adjacent in program order).
__global__ __launch_bounds__(512, 4) void attn_kernel(const ushort_t* __restrict__ Qb,
                                                      const ushort_t* __restrict__ Kb,
                                                      const ushort_t* __restrict__ VTb,
                                                      ushort_t* __restrict__ Ob) {
    const int fid = blockIdx.x;
    const int xcd = fid & 7;
    const int slot = fid >> 3;                 // 0..63
    const int qtile = slot & 7;                // 8 q-tiles of 256 rows
    const int bh = (xcd << 3) + (slot >> 3);   // per-XCD K/V working set ~4MB (L2-fit)
    const int q0 = qtile * 256;
    const int tid = threadIdx.x;
    const int lane = tid & 63;
    const int wid = tid >> 6;                  // 0..7
    const int q31 = lane & 31;
    const int hi = lane >> 5;
    const int rsw = q31 & 7;
    const int b = bh >> 4, h = bh & 15;

    const ushort_t* Q = Qb + (size_t)bh * 2048 * 64;
    const ushort_t* K = Kb + (size_t)bh * 2048 * 64;
    const ushort_t* VT = VTb + (size_t)bh * 64 * 2048;

    __shared__ ushort_t Ksh[4][64 * 64];   // K tile [k][d], chunk-swizzled content; buf = t&3
    __shared__ ushort_t Vsh[4][64 * 64];   // V^T tile [d][k], chunk-swizzled content

    const int qw = q0 + wid * 32;

    // Q B-fragments (col=q=lane&31, k-rows d = ds*16 + hi*8 + j) — resident all loop
    s16x8 qf[4];
#pragma unroll
    for (int ds = 0; ds < 4; ++ds)
        qf[ds] = *(const s16x8*)&Q[(size_t)(qw + q31) * 64 + ds * 16 + hi * 8];

    // ones B-fragment (bf16 1.0 = 0x3F80) for the P*1 row-sum MFMA
    s16x8 ones;
#pragma unroll
    for (int j = 0; j < 8; ++j) ones[j] = (short)0x3F80;

    f32x16 o[2] = {};          // O[q-rows][d = db*32 + q31]
    f32x16 la = {};            // row-sum accumulator; same C-layout as o (all cols identical)

    stage_tile(K, VT, Ksh[0], Vsh[0], 0, tid);
    stage_tile(K, VT, Ksh[1], Vsh[1], 64, tid);

    const float negmc = -MFIX * CSC;   // fixed softmax shift (exp2 domain)

    for (int i = 0; i < 16; ++i) {
        // drain the 4 loads for tiles 2i,2i+1 (issued one full interval ago)
        asm volatile("s_waitcnt vmcnt(0)" ::: "memory");
        __builtin_amdgcn_sched_barrier(0);
        __builtin_amdgcn_s_barrier();      // all waves done with interval i-1 => its 2 bufs free
        __builtin_amdgcn_sched_barrier(0);

        // stage tiles 2i+2, 2i+3 into the buffers consumed in interval i-1 (tail: clamped dups)
        {
            int sa0 = (2 * i + 2 <= 31) ? 2 * i + 2 : 31;
            int sa1 = (2 * i + 3 <= 31) ? 2 * i + 3 : 31;
            stage_tile(K, VT, Ksh[(2 * i + 2) & 3], Vsh[(2 * i + 2) & 3], sa0 * 64, tid);
            stage_tile(K, VT, Ksh[(2 * i + 3) & 3], Vsh[(2 * i + 3) & 3], sa1 * 64, tid);
        }

#pragma unroll
        for (int half = 0; half < 2; ++half) {
            const int t = 2 * i + half;
            const ushort_t* KB = Ksh[t & 3];
            const ushort_t* VB = Vsh[t & 3];

            // ---- per kb: QK^T(kb) -> exp/pack(kb); only ONE f32x16 score block live ----
            s16x8 pa[4];
#pragma unroll
            for (int kb = 0; kb < 2; ++kb) {
                f32x16 sa = (f32x16)0.f;
                __builtin_amdgcn_s_setprio(1);
#pragma unroll
                for (int ds = 0; ds < 4; ++ds) {
                    s16x8 kfr = *(const s16x8*)&KB[(kb * 32 + q31) * 64 + (((2 * ds + hi) ^ rsw) * 8)];
                    sa = __builtin_amdgcn_mfma_f32_32x32x16_bf16(kfr, qf[ds], sa, 0, 0, 0);
                }
                __builtin_amdgcn_s_setprio(0);

                float p[16];
#pragma unroll
                for (int r = 0; r < 16; ++r)
                    p[r] = exp2f(fmaf(sa[r], CSC, negmc));
#pragma unroll
                for (int s = 0; s < 2; ++s) {
                    unsigned a0 = cvt_pk_bf16(p[8 * s + 0], p[8 * s + 1]);
                    unsigned b0 = cvt_pk_bf16(p[8 * s + 4], p[8 * s + 5]);
                    unsigned a1 = cvt_pk_bf16(p[8 * s + 2], p[8 * s + 3]);
                    unsigned b1 = cvt_pk_bf16(p[8 * s + 6], p[8 * s + 7]);
                    uint2v w02 = pl32swap(a0, b0);   // -> word0, word2
                    uint2v w13 = pl32swap(a1, b1);   // -> word1, word3
                    union { unsigned u[4]; s16x8 v; } fr;
                    fr.u[0] = w02.x; fr.u[1] = w13.x; fr.u[2] = w02.y; fr.u[3] = w13.y;
                    pa[kb * 2 + s] = fr.v;
                }
            }

            // ---- PV: O[q][d] += P * V; la += P * 1 (row-sum on the matrix pipe) ----
            __builtin_amdgcn_s_setprio(1);
#pragma unroll
            for (int s = 0; s < 4; ++s) {
#pragma unroll
                for (int db = 0; db < 2; ++db) {
                    s16x8 vfr = *(const s16x8*)&VB[(db * 32 + q31) * 64 + (((2 * s + hi) ^ rsw) * 8)];
                    o[db] = __builtin_amdgcn_mfma_f32_32x32x16_bf16(pa[s], vfr, o[db], 0, 0, 0);
                }
                la = __builtin_amdgcn_mfma_f32_32x32x16_bf16(pa[s], ones, la, 0, 0, 0);
            }
            __builtin_amdgcn_s_setprio(0);

            // pin separation between the two bodies: keeps only ONE tile's state live
            __builtin_amdgcn_sched_barrier(0);
        }
    }

    // drain outstanding tail DMA before kernel end
    asm volatile("s_waitcnt vmcnt(0)" ::: "memory");

    // ---- epilogue: la[r] is l for the same C-layout row as o[*][r] -> direct normalize ----
#pragma unroll
    for (int g = 0; g < 4; ++g) {
#pragma unroll
        for (int j = 0; j < 4; ++j) {
            int r = g * 4 + j;
            float inv = 1.0f / la[r];
            int qrow = qw + hi * 4 + g * 8 + j;
            size_t base = ((size_t)(b * 2048 + qrow)) * 1024 + h * 64 + q31;
            Ob[base] = f2b(o[0][r] * inv);
            Ob[base + 32] = f2b(o[1][r] * inv);
        }
    }
}

// ---------------- launcher ----------------
extern "C" void kernel_launch(void* const* d_in, const int* in_sizes, int n_in,
                              void* d_out, int out_size, void* d_ws, size_t ws_size,
                              hipStream_t stream) {
    const float* x  = (const float*)d_in[0];
    const float* Wq = (const float*)d_in[1];
    const float* bq = (const float*)d_in[2];
    const float* Wk = (const float*)d_in[3];
    const float* bk = (const float*)d_in[4];
    const float* Wv = (const float*)d_in[5];
    const float* bv = (const float*)d_in[6];
    const float* Wo = (const float*)d_in[7];
    const float* bo = (const float*)d_in[8];
    float* out = (float*)d_out;

    const size_t XN = (size_t)8192 * 1024;
    const size_t WN = (size_t)1024 * 1024;

    ushort_t* Xb  = (ushort_t*)d_ws;
    ushort_t* Wqb = Xb + XN;
    ushort_t* Wkb = Wqb + WN;
    ushort_t* Wvb = Wkb + WN;
    ushort_t* Wob = Wvb + WN;
    ushort_t* Qb  = Wob + WN;
    ushort_t* Kb  = Qb + XN;
    ushort_t* VTb = Kb + XN;   // V transposed: [B,H,64,2048]
    ushort_t* Ob  = VTb + XN;

    cvt_kernel<<<(int)(XN / 4 / 256), 256, 0, stream>>>(x, Xb, (int)XN);
    dim3 gc((int)(WN / 4 / 256), 4);
    cvt4_kernel<<<gc, 256, 0, stream>>>(Wq, Wk, Wv, Wo, Wqb, Wkb, Wvb, Wob);

    dim3 g1(64, 24);
    gemm_qkv<<<g1, 256, 0, stream>>>(Xb, Wqb, Wkb, Wvb, bq, bk, bv, Qb, Kb, VTb);

    attn_kernel<<<512, 512, 0, stream>>>(Qb, Kb, VTb, Ob);

    dim3 g3(64, 8);
    gemm_out<<<g3, 256, 0, stream>>>(Ob, Wob, bo, out);
}